// Round 12
// baseline (12382.207 us; speedup 1.0000x reference)
//
#include <hip/hip_runtime.h>
#include <math.h>

#define B   256
#define LT  128
#define LP  64
#define DM  512
#define D3  1536
#define DPH 80
#define SCALE_F 0.044194173824159216f   // 1/sqrt(512)

__device__ __forceinline__ float dot4(float4 a, float4 b) {
    return a.x*b.x + a.y*b.y + a.z*b.z + a.w*b.w;
}
__device__ __forceinline__ float sigmoidf_(float x) {
    return 1.0f / (1.0f + expf(-x));
}

// ---------------------------------------------------------------------------
// Precompute G[r][n] = bias[n] + sum_j Emb[r][j] * W[n*wstride + woff + j]
// ---------------------------------------------------------------------------
__global__ __launch_bounds__(256) void precompG_kernel(
    const float* __restrict__ Emb, const float* __restrict__ W,
    const float* __restrict__ bias, float* __restrict__ G,
    int wstride, int woff)
{
    const int n  = blockIdx.x * 256 + threadIdx.x;
    const int r0 = blockIdx.y * 4;
    __shared__ float es[4][DM];
    for (int i = threadIdx.x; i < 4 * DM; i += 256)
        es[i >> 9][i & 511] = Emb[(r0 + (i >> 9)) * DM + (i & 511)];
    __syncthreads();
    float acc[4] = {0.f, 0.f, 0.f, 0.f};
    const float* wr = &W[(size_t)n * wstride + woff];
    for (int j = 0; j < DM; j += 4) {
        float4 w4 = *(const float4*)&wr[j];
        #pragma unroll
        for (int rr = 0; rr < 4; ++rr) {
            float4 e4 = *(const float4*)&es[rr][j];
            acc[rr] += dot4(e4, w4);
        }
    }
    float bv = bias[n];
    #pragma unroll
    for (int rr = 0; rr < 4; ++rr)
        G[(r0 + rr) * D3 + n] = acc[rr] + bv;
}

// ---------------------------------------------------------------------------
// Encoder GRU step: 32x32 output tile, per-thread 2 rows x 2 j-cols
// (48 FMA / 8 LDS reads). grid (16,8,2) = 256 blocks, 256 thr, dbuf 1-sync.
// ---------------------------------------------------------------------------
__global__ __launch_bounds__(256) void enc_step_kernel(
    const float* __restrict__ Gf, const float* __restrict__ Gb,
    const float* __restrict__ Whh_f, const float* __restrict__ Whh_b,
    const float* __restrict__ bhh_f, const float* __restrict__ bhh_b,
    const int* __restrict__ text,
    const float* __restrict__ hF_in, float* __restrict__ hF_out,
    const float* __restrict__ hB_in, float* __restrict__ hB_out,
    float* __restrict__ E, int s)
{
    const int dir = blockIdx.z;
    const int t   = dir ? (LT - 1 - s) : s;
    const int yoff = dir ? DM : 0;
    const float* G   = dir ? Gb : Gf;
    const float* Whh = dir ? Whh_b : Whh_f;
    const float* bhh = dir ? bhh_b : bhh_f;
    const float* hin = dir ? hB_in : hF_in;
    float* hout      = dir ? hB_out : hF_out;

    __shared__ float As[2][32][36];
    __shared__ float Bs[2][96][36];

    const int tid = threadIdx.x;
    const int jj  = tid & 15;
    const int bg  = tid >> 4;          // 0..15 -> rows bg*2+m
    const int jtile = blockIdx.x * 32;
    const int btile = blockIdx.y * 32;

    // prefetch gate-table rows + h_prev (hidden under GEMM)
    float pg[2][2][3], php[2][2];
    #pragma unroll
    for (int m = 0; m < 2; ++m) {
        const int b = btile + bg * 2 + m;
        const int c = text[b * LT + t];
        #pragma unroll
        for (int js = 0; js < 2; ++js) {
            const int j = jtile + jj + 16 * js;
            pg[m][js][0] = G[c * D3 + j];
            pg[m][js][1] = G[c * D3 + DM + j];
            pg[m][js][2] = G[c * D3 + 2 * DM + j];
            php[m][js]   = hin[b * DM + j];
        }
    }

    float acc[2][2][3];
    #pragma unroll
    for (int m = 0; m < 2; ++m)
        #pragma unroll
        for (int js = 0; js < 2; ++js)
            #pragma unroll
            for (int g = 0; g < 3; ++g) acc[m][js][g] = 0.f;

    const int lrow = tid >> 3;         // 0..31
    const int lcol = (tid & 7) * 4;
    size_t wbase[3];
    #pragma unroll
    for (int rr = 0; rr < 3; ++rr)
        wbase[rr] = (size_t)(rr * DM + jtile + lrow) * DM;

    float4 rA  = *(const float4*)&hin[(btile + lrow) * DM + lcol];
    float4 rB0 = *(const float4*)&Whh[wbase[0] + lcol];
    float4 rB1 = *(const float4*)&Whh[wbase[1] + lcol];
    float4 rB2 = *(const float4*)&Whh[wbase[2] + lcol];

    int buf = 0;
    for (int kc = 0; kc < 16; ++kc) {
        *(float4*)&As[buf][lrow][lcol]      = rA;
        *(float4*)&Bs[buf][lrow][lcol]      = rB0;
        *(float4*)&Bs[buf][lrow + 32][lcol] = rB1;
        *(float4*)&Bs[buf][lrow + 64][lcol] = rB2;
        __syncthreads();
        if (kc < 15) {
            const int k0 = (kc + 1) * 32;
            rA  = *(const float4*)&hin[(btile + lrow) * DM + k0 + lcol];
            rB0 = *(const float4*)&Whh[wbase[0] + k0 + lcol];
            rB1 = *(const float4*)&Whh[wbase[1] + k0 + lcol];
            rB2 = *(const float4*)&Whh[wbase[2] + k0 + lcol];
        }
        #pragma unroll
        for (int c4 = 0; c4 < 8; ++c4) {
            float4 av[2], bv[2][3];
            #pragma unroll
            for (int m = 0; m < 2; ++m)
                av[m] = *(float4*)&As[buf][bg * 2 + m][c4 * 4];
            #pragma unroll
            for (int js = 0; js < 2; ++js)
                #pragma unroll
                for (int g = 0; g < 3; ++g)
                    bv[js][g] = *(float4*)&Bs[buf][g * 32 + jj + 16 * js][c4 * 4];
            #pragma unroll
            for (int m = 0; m < 2; ++m)
                #pragma unroll
                for (int js = 0; js < 2; ++js)
                    #pragma unroll
                    for (int g = 0; g < 3; ++g)
                        acc[m][js][g] += dot4(av[m], bv[js][g]);
        }
        buf ^= 1;
    }

    #pragma unroll
    for (int m = 0; m < 2; ++m) {
        const int b = btile + bg * 2 + m;
        #pragma unroll
        for (int js = 0; js < 2; ++js) {
            const int j = jtile + jj + 16 * js;
            float hr = acc[m][js][0] + bhh[j];
            float hz = acc[m][js][1] + bhh[DM + j];
            float hn = acc[m][js][2] + bhh[2 * DM + j];
            float r = sigmoidf_(pg[m][js][0] + hr);
            float z = sigmoidf_(pg[m][js][1] + hz);
            float n = tanhf(pg[m][js][2] + r * hn);
            float hv = (1.f - z) * n + z * php[m][js];
            hout[b * DM + j] = hv;
            E[(size_t)(b * LT + t) * 1024 + yoff + j] = hv;
        }
    }
}

// ---------------------------------------------------------------------------
// Chunked k/v projection: 128-row M-tile (M=8 per thread), 64-col N-tile.
// grid (8, 128) per 16384-row chunk. 256 FMA / 128 LDS reads per c4-pass.
// Per-output accumulation chains identical to 64-tile version (bitwise).
// ---------------------------------------------------------------------------
__global__ __launch_bounds__(256) void kv_chunk_kernel(
    const float* __restrict__ E,
    const float* __restrict__ wk, const float* __restrict__ wv,
    const float* __restrict__ kb, const float* __restrict__ vb,
    float* __restrict__ T, int r0)
{
    __shared__ float As[128][36];
    __shared__ float Bk[64][36];
    __shared__ float Bv[64][36];
    const int tid = threadIdx.x;
    const int nn = tid & 15, bb = tid >> 4;
    const int ntile = blockIdx.x * 64;
    const int mtile = blockIdx.y * 128;

    float ak[8][4], av_[8][4];
    #pragma unroll
    for (int m = 0; m < 8; ++m)
        #pragma unroll
        for (int i = 0; i < 4; ++i) { ak[m][i] = 0.f; av_[m][i] = 0.f; }

    const int lrow = tid >> 3;
    const int lcol = (tid & 7) * 4;

    for (int k0 = 0; k0 < 1024; k0 += 32) {
        __syncthreads();
        #pragma unroll
        for (int q = 0; q < 4; ++q)
            *(float4*)&As[lrow + 32 * q][lcol] =
                *(const float4*)&E[(size_t)(r0 + mtile + lrow + 32 * q) * 1024 + k0 + lcol];
        *(float4*)&Bk[lrow][lcol] =
            *(const float4*)&wk[(ntile + lrow) * 1024 + k0 + lcol];
        *(float4*)&Bk[lrow + 32][lcol] =
            *(const float4*)&wk[(ntile + lrow + 32) * 1024 + k0 + lcol];
        *(float4*)&Bv[lrow][lcol] =
            *(const float4*)&wv[(ntile + lrow) * 1024 + k0 + lcol];
        *(float4*)&Bv[lrow + 32][lcol] =
            *(const float4*)&wv[(ntile + lrow + 32) * 1024 + k0 + lcol];
        __syncthreads();
        #pragma unroll
        for (int c4 = 0; c4 < 8; ++c4) {
            float4 a4[8], k4[4], v4[4];
            #pragma unroll
            for (int m = 0; m < 8; ++m) a4[m] = *(float4*)&As[bb + 16 * m][c4 * 4];
            #pragma unroll
            for (int i = 0; i < 4; ++i) {
                k4[i] = *(float4*)&Bk[nn + 16 * i][c4 * 4];
                v4[i] = *(float4*)&Bv[nn + 16 * i][c4 * 4];
            }
            #pragma unroll
            for (int m = 0; m < 8; ++m)
                #pragma unroll
                for (int i = 0; i < 4; ++i) {
                    ak[m][i]  += dot4(a4[m], k4[i]);
                    av_[m][i] += dot4(a4[m], v4[i]);
                }
        }
    }
    #pragma unroll
    for (int m = 0; m < 8; ++m) {
        const int lm = mtile + bb + 16 * m;
        #pragma unroll
        for (int i = 0; i < 4; ++i) {
            const int gn = ntile + nn + 16 * i;
            T[(size_t)lm * 1024 + gn]       = ak[m][i]  + kb[gn];
            T[(size_t)lm * 1024 + DM + gn]  = av_[m][i] + vb[gn];
        }
    }
}

__global__ __launch_bounds__(256) void copy4_kernel(
    float4* __restrict__ dst, const float4* __restrict__ src, int n4)
{
    int i = blockIdx.x * 256 + threadIdx.x;
    const int stride = gridDim.x * 256;
    for (; i < n4; i += stride) dst[i] = src[i];
}

// ---------------------------------------------------------------------------
// h0 = tanh([hF|hB] @ hpost_W.T + hpost_b). One block per batch row.
// ---------------------------------------------------------------------------
__global__ __launch_bounds__(256) void hpost_kernel(
    const float* __restrict__ hF, const float* __restrict__ hB,
    const float* __restrict__ W, const float* __restrict__ bias,
    float* __restrict__ out)
{
    const int b = blockIdx.x;
    __shared__ float as_[1024];
    for (int i = threadIdx.x; i < DM; i += 256) {
        as_[i]      = hF[b * DM + i];
        as_[DM + i] = hB[b * DM + i];
    }
    __syncthreads();
    for (int n = threadIdx.x; n < DM; n += 256) {
        const float* wr = &W[n * 1024];
        float acc = 0.f;
        for (int j = 0; j < 1024; j += 4)
            acc += dot4(*(const float4*)&as_[j], *(const float4*)&wr[j]);
        out[b * DM + n] = tanhf(acc + bias[n]);
    }
}

// ---------------------------------------------------------------------------
// Decoder GRU GEMM, phase-split: bz=0 -> a_o @ dec_Wih[:,512:],
// bz=1 -> h_in @ dec_Whh. 32x32 tile, 2x2 micro-tile, partials -> P.
// grid (16,8,2) = 256 blocks, 256 thr.
// ---------------------------------------------------------------------------
__global__ __launch_bounds__(256) void dec_step_kernel(
    const float* __restrict__ dec_Wih, const float* __restrict__ dec_Whh,
    const float* __restrict__ a_o, const float* __restrict__ h_in,
    float* __restrict__ P)
{
    const int ph = blockIdx.z;
    const float* Aptr = ph ? h_in : a_o;
    const float* Wsrc = ph ? dec_Whh : dec_Wih;
    const size_t wstride = ph ? 512 : 1024;
    const int woff = ph ? 0 : DM;

    __shared__ float As[2][32][36];
    __shared__ float Bs[2][96][36];

    const int tid = threadIdx.x;
    const int jj  = tid & 15;
    const int bg  = tid >> 4;
    const int jtile = blockIdx.x * 32;
    const int btile = blockIdx.y * 32;

    float acc[2][2][3];
    #pragma unroll
    for (int m = 0; m < 2; ++m)
        #pragma unroll
        for (int js = 0; js < 2; ++js)
            #pragma unroll
            for (int g = 0; g < 3; ++g) acc[m][js][g] = 0.f;

    const int lrow = tid >> 3;
    const int lcol = (tid & 7) * 4;
    size_t wbase[3];
    #pragma unroll
    for (int rr = 0; rr < 3; ++rr)
        wbase[rr] = (size_t)(rr * DM + jtile + lrow) * wstride + woff;

    float4 rA  = *(const float4*)&Aptr[(btile + lrow) * DM + lcol];
    float4 rB0 = *(const float4*)&Wsrc[wbase[0] + lcol];
    float4 rB1 = *(const float4*)&Wsrc[wbase[1] + lcol];
    float4 rB2 = *(const float4*)&Wsrc[wbase[2] + lcol];

    int buf = 0;
    for (int kc = 0; kc < 16; ++kc) {
        *(float4*)&As[buf][lrow][lcol]      = rA;
        *(float4*)&Bs[buf][lrow][lcol]      = rB0;
        *(float4*)&Bs[buf][lrow + 32][lcol] = rB1;
        *(float4*)&Bs[buf][lrow + 64][lcol] = rB2;
        __syncthreads();
        if (kc < 15) {
            const int k0 = (kc + 1) * 32;
            rA  = *(const float4*)&Aptr[(btile + lrow) * DM + k0 + lcol];
            rB0 = *(const float4*)&Wsrc[wbase[0] + k0 + lcol];
            rB1 = *(const float4*)&Wsrc[wbase[1] + k0 + lcol];
            rB2 = *(const float4*)&Wsrc[wbase[2] + k0 + lcol];
        }
        #pragma unroll
        for (int c4 = 0; c4 < 8; ++c4) {
            float4 av[2], bv[2][3];
            #pragma unroll
            for (int m = 0; m < 2; ++m)
                av[m] = *(float4*)&As[buf][bg * 2 + m][c4 * 4];
            #pragma unroll
            for (int js = 0; js < 2; ++js)
                #pragma unroll
                for (int g = 0; g < 3; ++g)
                    bv[js][g] = *(float4*)&Bs[buf][g * 32 + jj + 16 * js][c4 * 4];
            #pragma unroll
            for (int m = 0; m < 2; ++m)
                #pragma unroll
                for (int js = 0; js < 2; ++js)
                    #pragma unroll
                    for (int g = 0; g < 3; ++g)
                        acc[m][js][g] += dot4(av[m], bv[js][g]);
        }
        buf ^= 1;
    }

    float* Pp = P + (size_t)ph * B * 1536;
    #pragma unroll
    for (int m = 0; m < 2; ++m) {
        const int b = btile + bg * 2 + m;
        #pragma unroll
        for (int js = 0; js < 2; ++js) {
            const int j = jtile + jj + 16 * js;
            #pragma unroll
            for (int g = 0; g < 3; ++g)
                Pp[(size_t)b * 1536 + g * 512 + j] = acc[m][js][g];
        }
    }
}

// ---------------------------------------------------------------------------
// Decoder tail, 512 threads, one block per batch row:
// combine(P0+P1 -> gates -> x, h_out) | logits+argmax | quad-QK attention
// + quad-PV. K row r at EKV[r*1024], V at +512.
// ---------------------------------------------------------------------------
__global__ __launch_bounds__(512) void dec_attend_post_kernel(
    const float* __restrict__ P,
    const float* __restrict__ Gd, const float* __restrict__ dec_bhh,
    const float* __restrict__ h_in, float* __restrict__ h_out,
    const float* __restrict__ q_init,
    const float* __restrict__ EKV,
    const float* __restrict__ post_W, const float* __restrict__ post_b,
    float* __restrict__ attn, float* __restrict__ res,
    float* __restrict__ a_o, int* __restrict__ dec_i,
    int s, int attn_row, int do_combine, int do_post, int do_attn)
{
    const int b = blockIdx.x;
    const int tid = threadIdx.x;
    __shared__ float qs[DM];
    __shared__ float part[512];
    __shared__ float sarr[LT];
    __shared__ float red[2];
    __shared__ float4 pvp[4][128];

    if (do_combine) {
        const int j = tid;                       // 0..511
        const int c = dec_i[b];
        const float* P0 = P + (size_t)b * 1536;
        const float* P1 = P + (size_t)B * 1536 + (size_t)b * 1536;
        float rsum = P0[j] + P1[j];
        float zsum = P0[512 + j] + P1[512 + j];
        float r = sigmoidf_(Gd[c * D3 + j] + dec_bhh[j] + rsum);
        float z = sigmoidf_(Gd[c * D3 + DM + j] + dec_bhh[DM + j] + zsum);
        float n = tanhf(Gd[c * D3 + 2 * DM + j] + P0[1024 + j]
                        + r * (P1[1024 + j] + dec_bhh[2 * DM + j]));
        float x = (1.f - z) * n + z * h_in[b * DM + j];
        qs[j] = x;
        h_out[b * DM + j] = x;
    } else if (tid < 128) {
        *(float4*)&qs[tid * 4] = *(const float4*)&q_init[b * DM + tid * 4];
    }
    __syncthreads();

    if (do_post) {
        if (tid < DPH) {
            const float* wr = &post_W[tid * DM];
            float acc = 0.f;
            for (int d = 0; d < DM; d += 4)
                acc += dot4(*(const float4*)&qs[d], *(const float4*)&wr[d]);
            float lv = acc + post_b[tid];
            res[(size_t)(b * LP + s) * DPH + tid] = lv;
            part[tid] = lv;
        }
        __syncthreads();
        if (tid == 0) {   // first-occurrence argmax, matching jnp.argmax
            float best = part[0]; int bi = 0;
            for (int p = 1; p < DPH; ++p) {
                float vv = part[p];
                if (vv > best) { best = vv; bi = p; }
            }
            dec_i[b] = bi;
        }
        __syncthreads();
    }

    if (do_attn) {
        // --- scores: 4 threads per K-row (d-quarters) ---
        {
            const int r = tid & 127, quad = tid >> 7;
            const float* kr = &EKV[(size_t)(b * LT + r) * 1024 + quad * 128];
            const float* qh = &qs[quad * 128];
            float p0 = 0.f, p1 = 0.f;
            #pragma unroll
            for (int d = 0; d < 128; d += 8) {
                p0 += dot4(*(const float4*)&qh[d],     *(const float4*)&kr[d]);
                p1 += dot4(*(const float4*)&qh[d + 4], *(const float4*)&kr[d + 4]);
            }
            part[tid] = p0 + p1;
        }
        __syncthreads();
        if (tid < LT)
            sarr[tid] = (((part[tid] + part[tid + 128]) + part[tid + 256])
                         + part[tid + 384]) * SCALE_F;
        __syncthreads();
        if (tid < 64) {
            float m = fmaxf(sarr[tid], sarr[tid + 64]);
            #pragma unroll
            for (int off = 32; off > 0; off >>= 1)
                m = fmaxf(m, __shfl_xor(m, off));
            if (tid == 0) red[0] = m;
        }
        __syncthreads();
        const float smax = red[0];
        if (tid < LT) sarr[tid] = expf(sarr[tid] - smax);
        __syncthreads();
        if (tid < 64) {
            float ssum = sarr[tid] + sarr[tid + 64];
            #pragma unroll
            for (int off = 32; off > 0; off >>= 1)
                ssum += __shfl_xor(ssum, off);
            if (tid == 0) red[1] = ssum;
        }
        __syncthreads();
        const float inv = 1.0f / red[1];
        if (tid < LT) {
            float a = sarr[tid] * inv;
            sarr[tid] = a;
            attn[(size_t)(b * LP + attn_row) * LT + tid] = a;
        }
        __syncthreads();
        // --- o = a @ V: 4 threads per d-float4 (l-quarters) ---
        {
            const int d4 = tid & 127, quad = tid >> 7;
            const float* vb0 = &EKV[(size_t)b * LT * 1024 + DM];
            float4 a0 = make_float4(0.f, 0.f, 0.f, 0.f);
            float4 a1 = make_float4(0.f, 0.f, 0.f, 0.f);
            const int l0 = quad * 32;
            #pragma unroll
            for (int l = l0; l < l0 + 32; l += 2) {
                float w0 = sarr[l], w1 = sarr[l + 1];
                float4 v0 = *(const float4*)&vb0[(size_t)l * 1024 + d4 * 4];
                float4 v1 = *(const float4*)&vb0[(size_t)(l + 1) * 1024 + d4 * 4];
                a0.x += w0 * v0.x; a0.y += w0 * v0.y;
                a0.z += w0 * v0.z; a0.w += w0 * v0.w;
                a1.x += w1 * v1.x; a1.y += w1 * v1.y;
                a1.z += w1 * v1.z; a1.w += w1 * v1.w;
            }
            pvp[quad][d4] = make_float4(a0.x + a1.x, a0.y + a1.y,
                                        a0.z + a1.z, a0.w + a1.w);
        }
        __syncthreads();
        if (tid < 128) {
            float4 p0 = pvp[0][tid], p1 = pvp[1][tid];
            float4 p2 = pvp[2][tid], p3 = pvp[3][tid];
            float4 o = make_float4(((p0.x + p1.x) + p2.x) + p3.x,
                                   ((p0.y + p1.y) + p2.y) + p3.y,
                                   ((p0.z + p1.z) + p2.z) + p3.z,
                                   ((p0.w + p1.w) + p2.w) + p3.w);
            *(float4*)&a_o[b * DM + tid * 4] = o;
        }
    }
}

// ---------------------------------------------------------------------------
extern "C" void kernel_launch(void* const* d_in, const int* in_sizes, int n_in,
                              void* d_out, int out_size, void* d_ws, size_t ws_size,
                              hipStream_t stream)
{
    const int*   text    = (const int*)d_in[0];
    const float* E_alpha = (const float*)d_in[2];
    const float* Wih_f   = (const float*)d_in[3];
    const float* Whh_f   = (const float*)d_in[4];
    const float* bih_f   = (const float*)d_in[5];
    const float* bhh_f   = (const float*)d_in[6];
    const float* Wih_b   = (const float*)d_in[7];
    const float* Whh_b   = (const float*)d_in[8];
    const float* bih_b   = (const float*)d_in[9];
    const float* bhh_b   = (const float*)d_in[10];
    const float* hpost_W = (const float*)d_in[11];
    const float* hpost_b = (const float*)d_in[12];
    const float* wk_W    = (const float*)d_in[13];
    const float* wk_b    = (const float*)d_in[14];
    const float* wv_W    = (const float*)d_in[15];
    const float* wv_b    = (const float*)d_in[16];
    const float* E_ph    = (const float*)d_in[17];
    const float* dec_Wih = (const float*)d_in[18];
    const float* dec_Whh = (const float*)d_in[19];
    const float* dec_bih = (const float*)d_in[20];
    const float* dec_bhh = (const float*)d_in[21];
    const float* post_W  = (const float*)d_in[22];
    const float* post_b  = (const float*)d_in[23];

    float* ws = (float*)d_ws;
    float* Gf  = ws;                 // 100*1536
    float* Gb  = Gf  + 153600;
    float* Gd  = Gb  + 153600;       // 80*1536
    float* hF0 = Gd  + 122880;
    float* hF1 = hF0 + 131072;
    float* hB0 = hF1 + 131072;
    float* hB1 = hB0 + 131072;
    float* hd0 = hB1 + 131072;
    float* hd1 = hd0 + 131072;
    float* a_o = hd1 + 131072;
    int*   dec_i = (int*)(a_o + 131072);
    float* P   = a_o + 131072 + 512; // 2*256*1536 gate partials (3 MB)
    float* E   = P + 786432;         // 32768*1024: ys, then in-place K|V
    float* T   = E + 33554432;       // 16384*1024 chunk temp (64 MB)
    // ~200 MB total

    hipMemsetAsync(hF0, 0, 131072 * sizeof(float), stream);
    hipMemsetAsync(hB0, 0, 131072 * sizeof(float), stream);
    hipMemsetAsync(dec_i, 0, B * sizeof(int), stream);

    precompG_kernel<<<dim3(6, 25), 256, 0, stream>>>(E_alpha, Wih_f, bih_f, Gf, DM, 0);
    precompG_kernel<<<dim3(6, 25), 256, 0, stream>>>(E_alpha, Wih_b, bih_b, Gb, DM, 0);
    precompG_kernel<<<dim3(6, 20), 256, 0, stream>>>(E_ph, dec_Wih, dec_bih, Gd, 1024, 0);

    // Bidirectional encoder: 128 steps
    for (int s = 0; s < LT; ++s) {
        const float* fin = (s & 1) ? hF1 : hF0;
        float*       fou = (s & 1) ? hF0 : hF1;
        const float* bin = (s & 1) ? hB1 : hB0;
        float*       bou = (s & 1) ? hB0 : hB1;
        enc_step_kernel<<<dim3(16, 8, 2), 256, 0, stream>>>(
            Gf, Gb, Whh_f, Whh_b, bhh_f, bhh_b, text,
            fin, fou, bin, bou, E, s);
    }
    // s=127 wrote into hF0/hB0 -> finals live there

    for (int c = 0; c < 2; ++c) {
        const int r0 = c * 16384;
        kv_chunk_kernel<<<dim3(8, 128), 256, 0, stream>>>(
            E, wk_W, wv_W, wk_b, wv_b, T, r0);
        copy4_kernel<<<dim3(4096), 256, 0, stream>>>(
            (float4*)(E + (size_t)r0 * 1024), (const float4*)T,
            16384 * 1024 / 4);
    }

    hpost_kernel<<<dim3(B), 256, 0, stream>>>(hF0, hB0, hpost_W, hpost_b, hd0);

    float* attn = (float*)d_out;                  // (256,64,128)
    float* res  = attn + (size_t)B * LP * LT;     // (256,64,80)

    // initial attend: q = hd0 -> attn row 0 + a_o
    dec_attend_post_kernel<<<dim3(B), 512, 0, stream>>>(
        P, Gd, dec_bhh, hd0, hd1, hd0, E, post_W, post_b,
        attn, res, a_o, dec_i,
        /*s=*/0, /*attn_row=*/0, /*combine=*/0, /*post=*/0, /*attn=*/1);

    for (int s = 0; s < LP; ++s) {
        const float* hin = (s & 1) ? hd1 : hd0;
        float*       hou = (s & 1) ? hd0 : hd1;
        // phase-split GRU GEMM -> partials P
        dec_step_kernel<<<dim3(16, 8, 2), 256, 0, stream>>>(
            dec_Wih, dec_Whh, a_o, hin, P);
        // combine + gates + x write + logits/argmax + attention
        dec_attend_post_kernel<<<dim3(B), 512, 0, stream>>>(
            P, Gd, dec_bhh, hin, hou, hd0 /*unused*/, E, post_W, post_b,
            attn, res, a_o, dec_i,
            s, s + 1, /*combine=*/1, /*post=*/1, /*attn=*/(s < LP - 1) ? 1 : 0);
    }
}

// Round 13
// 10408.681 us; speedup vs baseline: 1.1896x; 1.1896x over previous
//
#include <hip/hip_runtime.h>
#include <math.h>

#define B   256
#define LT  128
#define LP  64
#define DM  512
#define D3  1536
#define DPH 80
#define SCALE_F 0.044194173824159216f   // 1/sqrt(512)

__device__ __forceinline__ float dot4(float4 a, float4 b) {
    return a.x*b.x + a.y*b.y + a.z*b.z + a.w*b.w;
}
__device__ __forceinline__ float sigmoidf_(float x) {
    return 1.0f / (1.0f + expf(-x));
}

// ---------------------------------------------------------------------------
// Precompute G[r][n] = bias[n] + sum_j Emb[r][j] * W[n*wstride + woff + j]
// ---------------------------------------------------------------------------
__global__ __launch_bounds__(256) void precompG_kernel(
    const float* __restrict__ Emb, const float* __restrict__ W,
    const float* __restrict__ bias, float* __restrict__ G,
    int wstride, int woff)
{
    const int n  = blockIdx.x * 256 + threadIdx.x;
    const int r0 = blockIdx.y * 4;
    __shared__ float es[4][DM];
    for (int i = threadIdx.x; i < 4 * DM; i += 256)
        es[i >> 9][i & 511] = Emb[(r0 + (i >> 9)) * DM + (i & 511)];
    __syncthreads();
    float acc[4] = {0.f, 0.f, 0.f, 0.f};
    const float* wr = &W[(size_t)n * wstride + woff];
    for (int j = 0; j < DM; j += 4) {
        float4 w4 = *(const float4*)&wr[j];
        #pragma unroll
        for (int rr = 0; rr < 4; ++rr) {
            float4 e4 = *(const float4*)&es[rr][j];
            acc[rr] += dot4(e4, w4);
        }
    }
    float bv = bias[n];
    #pragma unroll
    for (int rr = 0; rr < 4; ++rr)
        G[(r0 + rr) * D3 + n] = acc[rr] + bv;
}

// ---------------------------------------------------------------------------
// Encoder GRU step: 32x32 output tile, per-thread 2 rows x 2 j-cols
// (48 FMA / 8 LDS reads). grid (16,8,2) = 256 blocks, 256 thr, dbuf 1-sync.
// ---------------------------------------------------------------------------
__global__ __launch_bounds__(256) void enc_step_kernel(
    const float* __restrict__ Gf, const float* __restrict__ Gb,
    const float* __restrict__ Whh_f, const float* __restrict__ Whh_b,
    const float* __restrict__ bhh_f, const float* __restrict__ bhh_b,
    const int* __restrict__ text,
    const float* __restrict__ hF_in, float* __restrict__ hF_out,
    const float* __restrict__ hB_in, float* __restrict__ hB_out,
    float* __restrict__ E, int s)
{
    const int dir = blockIdx.z;
    const int t   = dir ? (LT - 1 - s) : s;
    const int yoff = dir ? DM : 0;
    const float* G   = dir ? Gb : Gf;
    const float* Whh = dir ? Whh_b : Whh_f;
    const float* bhh = dir ? bhh_b : bhh_f;
    const float* hin = dir ? hB_in : hF_in;
    float* hout      = dir ? hB_out : hF_out;

    __shared__ float As[2][32][36];
    __shared__ float Bs[2][96][36];

    const int tid = threadIdx.x;
    const int jj  = tid & 15;
    const int bg  = tid >> 4;          // 0..15 -> rows bg*2+m
    const int jtile = blockIdx.x * 32;
    const int btile = blockIdx.y * 32;

    // prefetch gate-table rows + h_prev (hidden under GEMM)
    float pg[2][2][3], php[2][2];
    #pragma unroll
    for (int m = 0; m < 2; ++m) {
        const int b = btile + bg * 2 + m;
        const int c = text[b * LT + t];
        #pragma unroll
        for (int js = 0; js < 2; ++js) {
            const int j = jtile + jj + 16 * js;
            pg[m][js][0] = G[c * D3 + j];
            pg[m][js][1] = G[c * D3 + DM + j];
            pg[m][js][2] = G[c * D3 + 2 * DM + j];
            php[m][js]   = hin[b * DM + j];
        }
    }

    float acc[2][2][3];
    #pragma unroll
    for (int m = 0; m < 2; ++m)
        #pragma unroll
        for (int js = 0; js < 2; ++js)
            #pragma unroll
            for (int g = 0; g < 3; ++g) acc[m][js][g] = 0.f;

    const int lrow = tid >> 3;         // 0..31
    const int lcol = (tid & 7) * 4;
    size_t wbase[3];
    #pragma unroll
    for (int rr = 0; rr < 3; ++rr)
        wbase[rr] = (size_t)(rr * DM + jtile + lrow) * DM;

    float4 rA  = *(const float4*)&hin[(btile + lrow) * DM + lcol];
    float4 rB0 = *(const float4*)&Whh[wbase[0] + lcol];
    float4 rB1 = *(const float4*)&Whh[wbase[1] + lcol];
    float4 rB2 = *(const float4*)&Whh[wbase[2] + lcol];

    int buf = 0;
    for (int kc = 0; kc < 16; ++kc) {
        *(float4*)&As[buf][lrow][lcol]      = rA;
        *(float4*)&Bs[buf][lrow][lcol]      = rB0;
        *(float4*)&Bs[buf][lrow + 32][lcol] = rB1;
        *(float4*)&Bs[buf][lrow + 64][lcol] = rB2;
        __syncthreads();
        if (kc < 15) {
            const int k0 = (kc + 1) * 32;
            rA  = *(const float4*)&hin[(btile + lrow) * DM + k0 + lcol];
            rB0 = *(const float4*)&Whh[wbase[0] + k0 + lcol];
            rB1 = *(const float4*)&Whh[wbase[1] + k0 + lcol];
            rB2 = *(const float4*)&Whh[wbase[2] + k0 + lcol];
        }
        #pragma unroll
        for (int c4 = 0; c4 < 8; ++c4) {
            float4 av[2], bv[2][3];
            #pragma unroll
            for (int m = 0; m < 2; ++m)
                av[m] = *(float4*)&As[buf][bg * 2 + m][c4 * 4];
            #pragma unroll
            for (int js = 0; js < 2; ++js)
                #pragma unroll
                for (int g = 0; g < 3; ++g)
                    bv[js][g] = *(float4*)&Bs[buf][g * 32 + jj + 16 * js][c4 * 4];
            #pragma unroll
            for (int m = 0; m < 2; ++m)
                #pragma unroll
                for (int js = 0; js < 2; ++js)
                    #pragma unroll
                    for (int g = 0; g < 3; ++g)
                        acc[m][js][g] += dot4(av[m], bv[js][g]);
        }
        buf ^= 1;
    }

    #pragma unroll
    for (int m = 0; m < 2; ++m) {
        const int b = btile + bg * 2 + m;
        #pragma unroll
        for (int js = 0; js < 2; ++js) {
            const int j = jtile + jj + 16 * js;
            float hr = acc[m][js][0] + bhh[j];
            float hz = acc[m][js][1] + bhh[DM + j];
            float hn = acc[m][js][2] + bhh[2 * DM + j];
            float r = sigmoidf_(pg[m][js][0] + hr);
            float z = sigmoidf_(pg[m][js][1] + hz);
            float n = tanhf(pg[m][js][2] + r * hn);
            float hv = (1.f - z) * n + z * php[m][js];
            hout[b * DM + j] = hv;
            E[(size_t)(b * LT + t) * 1024 + yoff + j] = hv;
        }
    }
}

// ---------------------------------------------------------------------------
// Chunked k/v projection (rows [r0, r0+16384)) -> temp T, then copy4 back.
// 64x64 tile (R10-proven config).
// ---------------------------------------------------------------------------
__global__ __launch_bounds__(256) void kv_chunk_kernel(
    const float* __restrict__ E,
    const float* __restrict__ wk, const float* __restrict__ wv,
    const float* __restrict__ kb, const float* __restrict__ vb,
    float* __restrict__ T, int r0)
{
    __shared__ float As[64][36];
    __shared__ float Bk[64][36];
    __shared__ float Bv[64][36];
    const int tid = threadIdx.x;
    const int nn = tid & 15, bb = tid >> 4;
    const int ntile = blockIdx.x * 64;
    const int mtile = blockIdx.y * 64;

    float ak[4][4], av_[4][4];
    #pragma unroll
    for (int m = 0; m < 4; ++m)
        #pragma unroll
        for (int i = 0; i < 4; ++i) { ak[m][i] = 0.f; av_[m][i] = 0.f; }

    const int lrow = tid >> 3;
    const int lcol = (tid & 7) * 4;

    for (int k0 = 0; k0 < 1024; k0 += 32) {
        __syncthreads();
        *(float4*)&As[lrow][lcol] =
            *(const float4*)&E[(size_t)(r0 + mtile + lrow) * 1024 + k0 + lcol];
        *(float4*)&As[lrow + 32][lcol] =
            *(const float4*)&E[(size_t)(r0 + mtile + lrow + 32) * 1024 + k0 + lcol];
        *(float4*)&Bk[lrow][lcol] =
            *(const float4*)&wk[(ntile + lrow) * 1024 + k0 + lcol];
        *(float4*)&Bk[lrow + 32][lcol] =
            *(const float4*)&wk[(ntile + lrow + 32) * 1024 + k0 + lcol];
        *(float4*)&Bv[lrow][lcol] =
            *(const float4*)&wv[(ntile + lrow) * 1024 + k0 + lcol];
        *(float4*)&Bv[lrow + 32][lcol] =
            *(const float4*)&wv[(ntile + lrow + 32) * 1024 + k0 + lcol];
        __syncthreads();
        #pragma unroll
        for (int c4 = 0; c4 < 8; ++c4) {
            float4 a4[4], k4[4], v4[4];
            #pragma unroll
            for (int m = 0; m < 4; ++m) a4[m] = *(float4*)&As[bb + 16 * m][c4 * 4];
            #pragma unroll
            for (int i = 0; i < 4; ++i) {
                k4[i] = *(float4*)&Bk[nn + 16 * i][c4 * 4];
                v4[i] = *(float4*)&Bv[nn + 16 * i][c4 * 4];
            }
            #pragma unroll
            for (int m = 0; m < 4; ++m)
                #pragma unroll
                for (int i = 0; i < 4; ++i) {
                    ak[m][i]  += dot4(a4[m], k4[i]);
                    av_[m][i] += dot4(a4[m], v4[i]);
                }
        }
    }
    #pragma unroll
    for (int m = 0; m < 4; ++m) {
        const int lm = mtile + bb + 16 * m;
        #pragma unroll
        for (int i = 0; i < 4; ++i) {
            const int gn = ntile + nn + 16 * i;
            T[(size_t)lm * 1024 + gn]       = ak[m][i]  + kb[gn];
            T[(size_t)lm * 1024 + DM + gn]  = av_[m][i] + vb[gn];
        }
    }
}

__global__ __launch_bounds__(256) void copy4_kernel(
    float4* __restrict__ dst, const float4* __restrict__ src, int n4)
{
    int i = blockIdx.x * 256 + threadIdx.x;
    const int stride = gridDim.x * 256;
    for (; i < n4; i += stride) dst[i] = src[i];
}

// ---------------------------------------------------------------------------
// h0 = tanh([hF|hB] @ hpost_W.T + hpost_b). One block per batch row.
// ---------------------------------------------------------------------------
__global__ __launch_bounds__(256) void hpost_kernel(
    const float* __restrict__ hF, const float* __restrict__ hB,
    const float* __restrict__ W, const float* __restrict__ bias,
    float* __restrict__ out)
{
    const int b = blockIdx.x;
    __shared__ float as_[1024];
    for (int i = threadIdx.x; i < DM; i += 256) {
        as_[i]      = hF[b * DM + i];
        as_[DM + i] = hB[b * DM + i];
    }
    __syncthreads();
    for (int n = threadIdx.x; n < DM; n += 256) {
        const float* wr = &W[n * 1024];
        float acc = 0.f;
        for (int j = 0; j < 1024; j += 4)
            acc += dot4(*(const float4*)&as_[j], *(const float4*)&wr[j]);
        out[b * DM + n] = tanhf(acc + bias[n]);
    }
}

// ---------------------------------------------------------------------------
// Decoder GRU GEMM, phase+k-split: bz = ph*2 + kq.
// ph0: a_o @ dec_Wih[:,512:], ph1: h_in @ dec_Whh; kq selects k-half
// [kq*256, kq*256+256). 32x32 tile, 2x2 micro-tile, partials -> P slab bz.
// grid (16,8,4) = 512 blocks (2 blocks/CU), 256 thr.
// ---------------------------------------------------------------------------
__global__ __launch_bounds__(256) void dec_step_kernel(
    const float* __restrict__ dec_Wih, const float* __restrict__ dec_Whh,
    const float* __restrict__ a_o, const float* __restrict__ h_in,
    float* __restrict__ P)
{
    const int bz = blockIdx.z;
    const int ph = bz >> 1;
    const int kq = bz & 1;
    const float* Aptr = ph ? h_in : a_o;
    const float* Wsrc = ph ? dec_Whh : dec_Wih;
    const size_t wstride = ph ? 512 : 1024;
    const int woff = ph ? 0 : DM;
    const int kbase = kq * 256;

    __shared__ float As[2][32][36];
    __shared__ float Bs[2][96][36];

    const int tid = threadIdx.x;
    const int jj  = tid & 15;
    const int bg  = tid >> 4;
    const int jtile = blockIdx.x * 32;
    const int btile = blockIdx.y * 32;

    float acc[2][2][3];
    #pragma unroll
    for (int m = 0; m < 2; ++m)
        #pragma unroll
        for (int js = 0; js < 2; ++js)
            #pragma unroll
            for (int g = 0; g < 3; ++g) acc[m][js][g] = 0.f;

    const int lrow = tid >> 3;
    const int lcol = (tid & 7) * 4;
    size_t wbase[3];
    #pragma unroll
    for (int rr = 0; rr < 3; ++rr)
        wbase[rr] = (size_t)(rr * DM + jtile + lrow) * wstride + woff + kbase;

    float4 rA  = *(const float4*)&Aptr[(btile + lrow) * DM + kbase + lcol];
    float4 rB0 = *(const float4*)&Wsrc[wbase[0] + lcol];
    float4 rB1 = *(const float4*)&Wsrc[wbase[1] + lcol];
    float4 rB2 = *(const float4*)&Wsrc[wbase[2] + lcol];

    int buf = 0;
    for (int kc = 0; kc < 8; ++kc) {
        *(float4*)&As[buf][lrow][lcol]      = rA;
        *(float4*)&Bs[buf][lrow][lcol]      = rB0;
        *(float4*)&Bs[buf][lrow + 32][lcol] = rB1;
        *(float4*)&Bs[buf][lrow + 64][lcol] = rB2;
        __syncthreads();
        if (kc < 7) {
            const int k0 = (kc + 1) * 32;
            rA  = *(const float4*)&Aptr[(btile + lrow) * DM + kbase + k0 + lcol];
            rB0 = *(const float4*)&Wsrc[wbase[0] + k0 + lcol];
            rB1 = *(const float4*)&Wsrc[wbase[1] + k0 + lcol];
            rB2 = *(const float4*)&Wsrc[wbase[2] + k0 + lcol];
        }
        #pragma unroll
        for (int c4 = 0; c4 < 8; ++c4) {
            float4 av[2], bv[2][3];
            #pragma unroll
            for (int m = 0; m < 2; ++m)
                av[m] = *(float4*)&As[buf][bg * 2 + m][c4 * 4];
            #pragma unroll
            for (int js = 0; js < 2; ++js)
                #pragma unroll
                for (int g = 0; g < 3; ++g)
                    bv[js][g] = *(float4*)&Bs[buf][g * 32 + jj + 16 * js][c4 * 4];
            #pragma unroll
            for (int m = 0; m < 2; ++m)
                #pragma unroll
                for (int js = 0; js < 2; ++js)
                    #pragma unroll
                    for (int g = 0; g < 3; ++g)
                        acc[m][js][g] += dot4(av[m], bv[js][g]);
        }
        buf ^= 1;
    }

    float* Pp = P + (size_t)bz * B * 1536;
    #pragma unroll
    for (int m = 0; m < 2; ++m) {
        const int b = btile + bg * 2 + m;
        #pragma unroll
        for (int js = 0; js < 2; ++js) {
            const int j = jtile + jj + 16 * js;
            #pragma unroll
            for (int g = 0; g < 3; ++g)
                Pp[(size_t)b * 1536 + g * 512 + j] = acc[m][js][g];
        }
    }
}

// ---------------------------------------------------------------------------
// Decoder tail, 512 threads, one block per batch row:
// combine(4 P slabs -> gates -> x, h_out) | logits+argmax | quad-QK
// attention + quad-PV. K row r at EKV[r*1024], V at +512.
// ---------------------------------------------------------------------------
__global__ __launch_bounds__(512) void dec_attend_post_kernel(
    const float* __restrict__ P,
    const float* __restrict__ Gd, const float* __restrict__ dec_bhh,
    const float* __restrict__ h_in, float* __restrict__ h_out,
    const float* __restrict__ q_init,
    const float* __restrict__ EKV,
    const float* __restrict__ post_W, const float* __restrict__ post_b,
    float* __restrict__ attn, float* __restrict__ res,
    float* __restrict__ a_o, int* __restrict__ dec_i,
    int s, int attn_row, int do_combine, int do_post, int do_attn)
{
    const int b = blockIdx.x;
    const int tid = threadIdx.x;
    __shared__ float qs[DM];
    __shared__ float part[512];
    __shared__ float sarr[LT];
    __shared__ float red[2];
    __shared__ float4 pvp[4][128];

    if (do_combine) {
        const int j = tid;                       // 0..511
        const int c = dec_i[b];
        const float* P00 = P + (size_t)b * 1536;                    // ph0 k0
        const float* P01 = P + (size_t)(B + b) * 1536;              // ph0 k1
        const float* P10 = P + (size_t)(2 * B + b) * 1536;          // ph1 k0
        const float* P11 = P + (size_t)(3 * B + b) * 1536;          // ph1 k1
        float rsum = (P00[j] + P01[j]) + (P10[j] + P11[j]);
        float zsum = (P00[512 + j] + P01[512 + j]) + (P10[512 + j] + P11[512 + j]);
        float inn  = P00[1024 + j] + P01[1024 + j];
        float hn   = P10[1024 + j] + P11[1024 + j];
        float r = sigmoidf_(Gd[c * D3 + j] + dec_bhh[j] + rsum);
        float z = sigmoidf_(Gd[c * D3 + DM + j] + dec_bhh[DM + j] + zsum);
        float n = tanhf(Gd[c * D3 + 2 * DM + j] + inn
                        + r * (hn + dec_bhh[2 * DM + j]));
        float x = (1.f - z) * n + z * h_in[b * DM + j];
        qs[j] = x;
        h_out[b * DM + j] = x;
    } else if (tid < 128) {
        *(float4*)&qs[tid * 4] = *(const float4*)&q_init[b * DM + tid * 4];
    }
    __syncthreads();

    if (do_post) {
        if (tid < DPH) {
            const float* wr = &post_W[tid * DM];
            float acc = 0.f;
            for (int d = 0; d < DM; d += 4)
                acc += dot4(*(const float4*)&qs[d], *(const float4*)&wr[d]);
            float lv = acc + post_b[tid];
            res[(size_t)(b * LP + s) * DPH + tid] = lv;
            part[tid] = lv;
        }
        __syncthreads();
        if (tid == 0) {   // first-occurrence argmax, matching jnp.argmax
            float best = part[0]; int bi = 0;
            for (int p = 1; p < DPH; ++p) {
                float vv = part[p];
                if (vv > best) { best = vv; bi = p; }
            }
            dec_i[b] = bi;
        }
        __syncthreads();
    }

    if (do_attn) {
        // --- scores: 4 threads per K-row (d-quarters) ---
        {
            const int r = tid & 127, quad = tid >> 7;
            const float* kr = &EKV[(size_t)(b * LT + r) * 1024 + quad * 128];
            const float* qh = &qs[quad * 128];
            float p0 = 0.f, p1 = 0.f;
            #pragma unroll
            for (int d = 0; d < 128; d += 8) {
                p0 += dot4(*(const float4*)&qh[d],     *(const float4*)&kr[d]);
                p1 += dot4(*(const float4*)&qh[d + 4], *(const float4*)&kr[d + 4]);
            }
            part[tid] = p0 + p1;
        }
        __syncthreads();
        if (tid < LT)
            sarr[tid] = (((part[tid] + part[tid + 128]) + part[tid + 256])
                         + part[tid + 384]) * SCALE_F;
        __syncthreads();
        if (tid < 64) {
            float m = fmaxf(sarr[tid], sarr[tid + 64]);
            #pragma unroll
            for (int off = 32; off > 0; off >>= 1)
                m = fmaxf(m, __shfl_xor(m, off));
            if (tid == 0) red[0] = m;
        }
        __syncthreads();
        const float smax = red[0];
        if (tid < LT) sarr[tid] = expf(sarr[tid] - smax);
        __syncthreads();
        if (tid < 64) {
            float ssum = sarr[tid] + sarr[tid + 64];
            #pragma unroll
            for (int off = 32; off > 0; off >>= 1)
                ssum += __shfl_xor(ssum, off);
            if (tid == 0) red[1] = ssum;
        }
        __syncthreads();
        const float inv = 1.0f / red[1];
        if (tid < LT) {
            float a = sarr[tid] * inv;
            sarr[tid] = a;
            attn[(size_t)(b * LP + attn_row) * LT + tid] = a;
        }
        __syncthreads();
        // --- o = a @ V: 4 threads per d-float4 (l-quarters) ---
        {
            const int d4 = tid & 127, quad = tid >> 7;
            const float* vb0 = &EKV[(size_t)b * LT * 1024 + DM];
            float4 a0 = make_float4(0.f, 0.f, 0.f, 0.f);
            float4 a1 = make_float4(0.f, 0.f, 0.f, 0.f);
            const int l0 = quad * 32;
            #pragma unroll
            for (int l = l0; l < l0 + 32; l += 2) {
                float w0 = sarr[l], w1 = sarr[l + 1];
                float4 v0 = *(const float4*)&vb0[(size_t)l * 1024 + d4 * 4];
                float4 v1 = *(const float4*)&vb0[(size_t)(l + 1) * 1024 + d4 * 4];
                a0.x += w0 * v0.x; a0.y += w0 * v0.y;
                a0.z += w0 * v0.z; a0.w += w0 * v0.w;
                a1.x += w1 * v1.x; a1.y += w1 * v1.y;
                a1.z += w1 * v1.z; a1.w += w1 * v1.w;
            }
            pvp[quad][d4] = make_float4(a0.x + a1.x, a0.y + a1.y,
                                        a0.z + a1.z, a0.w + a1.w);
        }
        __syncthreads();
        if (tid < 128) {
            float4 p0 = pvp[0][tid], p1 = pvp[1][tid];
            float4 p2 = pvp[2][tid], p3 = pvp[3][tid];
            float4 o = make_float4(((p0.x + p1.x) + p2.x) + p3.x,
                                   ((p0.y + p1.y) + p2.y) + p3.y,
                                   ((p0.z + p1.z) + p2.z) + p3.z,
                                   ((p0.w + p1.w) + p2.w) + p3.w);
            *(float4*)&a_o[b * DM + tid * 4] = o;
        }
    }
}

// ---------------------------------------------------------------------------
extern "C" void kernel_launch(void* const* d_in, const int* in_sizes, int n_in,
                              void* d_out, int out_size, void* d_ws, size_t ws_size,
                              hipStream_t stream)
{
    const int*   text    = (const int*)d_in[0];
    const float* E_alpha = (const float*)d_in[2];
    const float* Wih_f   = (const float*)d_in[3];
    const float* Whh_f   = (const float*)d_in[4];
    const float* bih_f   = (const float*)d_in[5];
    const float* bhh_f   = (const float*)d_in[6];
    const float* Wih_b   = (const float*)d_in[7];
    const float* Whh_b   = (const float*)d_in[8];
    const float* bih_b   = (const float*)d_in[9];
    const float* bhh_b   = (const float*)d_in[10];
    const float* hpost_W = (const float*)d_in[11];
    const float* hpost_b = (const float*)d_in[12];
    const float* wk_W    = (const float*)d_in[13];
    const float* wk_b    = (const float*)d_in[14];
    const float* wv_W    = (const float*)d_in[15];
    const float* wv_b    = (const float*)d_in[16];
    const float* E_ph    = (const float*)d_in[17];
    const float* dec_Wih = (const float*)d_in[18];
    const float* dec_Whh = (const float*)d_in[19];
    const float* dec_bih = (const float*)d_in[20];
    const float* dec_bhh = (const float*)d_in[21];
    const float* post_W  = (const float*)d_in[22];
    const float* post_b  = (const float*)d_in[23];

    float* ws = (float*)d_ws;
    float* Gf  = ws;                 // 100*1536
    float* Gb  = Gf  + 153600;
    float* Gd  = Gb  + 153600;       // 80*1536
    float* hF0 = Gd  + 122880;
    float* hF1 = hF0 + 131072;
    float* hB0 = hF1 + 131072;
    float* hB1 = hB0 + 131072;
    float* hd0 = hB1 + 131072;
    float* hd1 = hd0 + 131072;
    float* a_o = hd1 + 131072;
    int*   dec_i = (int*)(a_o + 131072);
    float* P   = a_o + 131072 + 512; // 4*256*1536 gate partials (6 MB)
    float* E   = P + 1572864;        // 32768*1024: ys, then in-place K|V
    float* T   = E + 33554432;       // 16384*1024 chunk temp (64 MB)
    // ~203 MB total

    hipMemsetAsync(hF0, 0, 131072 * sizeof(float), stream);
    hipMemsetAsync(hB0, 0, 131072 * sizeof(float), stream);
    hipMemsetAsync(dec_i, 0, B * sizeof(int), stream);

    precompG_kernel<<<dim3(6, 25), 256, 0, stream>>>(E_alpha, Wih_f, bih_f, Gf, DM, 0);
    precompG_kernel<<<dim3(6, 25), 256, 0, stream>>>(E_alpha, Wih_b, bih_b, Gb, DM, 0);
    precompG_kernel<<<dim3(6, 20), 256, 0, stream>>>(E_ph, dec_Wih, dec_bih, Gd, 1024, 0);

    // Bidirectional encoder: 128 steps
    for (int s = 0; s < LT; ++s) {
        const float* fin = (s & 1) ? hF1 : hF0;
        float*       fou = (s & 1) ? hF0 : hF1;
        const float* bin = (s & 1) ? hB1 : hB0;
        float*       bou = (s & 1) ? hB0 : hB1;
        enc_step_kernel<<<dim3(16, 8, 2), 256, 0, stream>>>(
            Gf, Gb, Whh_f, Whh_b, bhh_f, bhh_b, text,
            fin, fou, bin, bou, E, s);
    }
    // s=127 wrote into hF0/hB0 -> finals live there

    for (int c = 0; c < 2; ++c) {
        const int r0 = c * 16384;
        kv_chunk_kernel<<<dim3(8, 256), 256, 0, stream>>>(
            E, wk_W, wv_W, wk_b, wv_b, T, r0);
        copy4_kernel<<<dim3(4096), 256, 0, stream>>>(
            (float4*)(E + (size_t)r0 * 1024), (const float4*)T,
            16384 * 1024 / 4);
    }

    hpost_kernel<<<dim3(B), 256, 0, stream>>>(hF0, hB0, hpost_W, hpost_b, hd0);

    float* attn = (float*)d_out;                  // (256,64,128)
    float* res  = attn + (size_t)B * LP * LT;     // (256,64,80)

    // initial attend: q = hd0 -> attn row 0 + a_o
    dec_attend_post_kernel<<<dim3(B), 512, 0, stream>>>(
        P, Gd, dec_bhh, hd0, hd1, hd0, E, post_W, post_b,
        attn, res, a_o, dec_i,
        /*s=*/0, /*attn_row=*/0, /*combine=*/0, /*post=*/0, /*attn=*/1);

    for (int s = 0; s < LP; ++s) {
        const float* hin = (s & 1) ? hd1 : hd0;
        float*       hou = (s & 1) ? hd0 : hd1;
        // phase+k-split GRU GEMM -> 4 partial slabs in P
        dec_step_kernel<<<dim3(16, 8, 4), 256, 0, stream>>>(
            dec_Wih, dec_Whh, a_o, hin, P);
        // combine + gates + x write + logits/argmax + attention
        dec_attend_post_kernel<<<dim3(B), 512, 0, stream>>>(
            P, Gd, dec_bhh, hin, hou, hd0 /*unused*/, E, post_W, post_b,
            attn, res, a_o, dec_i,
            s, s + 1, /*combine=*/1, /*post=*/1, /*attn=*/(s < LP - 1) ? 1 : 0);
    }
}

// Round 14
// 10286.518 us; speedup vs baseline: 1.2037x; 1.0119x over previous
//
#include <hip/hip_runtime.h>
#include <math.h>

#define B   256
#define LT  128
#define LP  64
#define DM  512
#define D3  1536
#define DPH 80
#define SCALE_F 0.044194173824159216f   // 1/sqrt(512)

__device__ __forceinline__ float dot4(float4 a, float4 b) {
    return a.x*b.x + a.y*b.y + a.z*b.z + a.w*b.w;
}
__device__ __forceinline__ float sigmoidf_(float x) {
    return 1.0f / (1.0f + expf(-x));
}

// ---------------------------------------------------------------------------
// Precompute G[r][n] = bias[n] + sum_j Emb[r][j] * W[n*wstride + woff + j]
// ---------------------------------------------------------------------------
__global__ __launch_bounds__(256) void precompG_kernel(
    const float* __restrict__ Emb, const float* __restrict__ W,
    const float* __restrict__ bias, float* __restrict__ G,
    int wstride, int woff)
{
    const int n  = blockIdx.x * 256 + threadIdx.x;
    const int r0 = blockIdx.y * 4;
    __shared__ float es[4][DM];
    for (int i = threadIdx.x; i < 4 * DM; i += 256)
        es[i >> 9][i & 511] = Emb[(r0 + (i >> 9)) * DM + (i & 511)];
    __syncthreads();
    float acc[4] = {0.f, 0.f, 0.f, 0.f};
    const float* wr = &W[(size_t)n * wstride + woff];
    for (int j = 0; j < DM; j += 4) {
        float4 w4 = *(const float4*)&wr[j];
        #pragma unroll
        for (int rr = 0; rr < 4; ++rr) {
            float4 e4 = *(const float4*)&es[rr][j];
            acc[rr] += dot4(e4, w4);
        }
    }
    float bv = bias[n];
    #pragma unroll
    for (int rr = 0; rr < 4; ++rr)
        G[(r0 + rr) * D3 + n] = acc[rr] + bv;
}

// ---------------------------------------------------------------------------
// Encoder GRU step: 32x32 output tile, per-thread 2 rows x 2 j-cols
// (48 FMA / 8 LDS reads). grid (16,8,2) = 256 blocks, 256 thr, dbuf 1-sync.
// ---------------------------------------------------------------------------
__global__ __launch_bounds__(256) void enc_step_kernel(
    const float* __restrict__ Gf, const float* __restrict__ Gb,
    const float* __restrict__ Whh_f, const float* __restrict__ Whh_b,
    const float* __restrict__ bhh_f, const float* __restrict__ bhh_b,
    const int* __restrict__ text,
    const float* __restrict__ hF_in, float* __restrict__ hF_out,
    const float* __restrict__ hB_in, float* __restrict__ hB_out,
    float* __restrict__ E, int s)
{
    const int dir = blockIdx.z;
    const int t   = dir ? (LT - 1 - s) : s;
    const int yoff = dir ? DM : 0;
    const float* G   = dir ? Gb : Gf;
    const float* Whh = dir ? Whh_b : Whh_f;
    const float* bhh = dir ? bhh_b : bhh_f;
    const float* hin = dir ? hB_in : hF_in;
    float* hout      = dir ? hB_out : hF_out;

    __shared__ float As[2][32][36];
    __shared__ float Bs[2][96][36];

    const int tid = threadIdx.x;
    const int jj  = tid & 15;
    const int bg  = tid >> 4;          // 0..15 -> rows bg*2+m
    const int jtile = blockIdx.x * 32;
    const int btile = blockIdx.y * 32;

    // prefetch gate-table rows + h_prev (hidden under GEMM)
    float pg[2][2][3], php[2][2];
    #pragma unroll
    for (int m = 0; m < 2; ++m) {
        const int b = btile + bg * 2 + m;
        const int c = text[b * LT + t];
        #pragma unroll
        for (int js = 0; js < 2; ++js) {
            const int j = jtile + jj + 16 * js;
            pg[m][js][0] = G[c * D3 + j];
            pg[m][js][1] = G[c * D3 + DM + j];
            pg[m][js][2] = G[c * D3 + 2 * DM + j];
            php[m][js]   = hin[b * DM + j];
        }
    }

    float acc[2][2][3];
    #pragma unroll
    for (int m = 0; m < 2; ++m)
        #pragma unroll
        for (int js = 0; js < 2; ++js)
            #pragma unroll
            for (int g = 0; g < 3; ++g) acc[m][js][g] = 0.f;

    const int lrow = tid >> 3;         // 0..31
    const int lcol = (tid & 7) * 4;
    size_t wbase[3];
    #pragma unroll
    for (int rr = 0; rr < 3; ++rr)
        wbase[rr] = (size_t)(rr * DM + jtile + lrow) * DM;

    float4 rA  = *(const float4*)&hin[(btile + lrow) * DM + lcol];
    float4 rB0 = *(const float4*)&Whh[wbase[0] + lcol];
    float4 rB1 = *(const float4*)&Whh[wbase[1] + lcol];
    float4 rB2 = *(const float4*)&Whh[wbase[2] + lcol];

    int buf = 0;
    for (int kc = 0; kc < 16; ++kc) {
        *(float4*)&As[buf][lrow][lcol]      = rA;
        *(float4*)&Bs[buf][lrow][lcol]      = rB0;
        *(float4*)&Bs[buf][lrow + 32][lcol] = rB1;
        *(float4*)&Bs[buf][lrow + 64][lcol] = rB2;
        __syncthreads();
        if (kc < 15) {
            const int k0 = (kc + 1) * 32;
            rA  = *(const float4*)&hin[(btile + lrow) * DM + k0 + lcol];
            rB0 = *(const float4*)&Whh[wbase[0] + k0 + lcol];
            rB1 = *(const float4*)&Whh[wbase[1] + k0 + lcol];
            rB2 = *(const float4*)&Whh[wbase[2] + k0 + lcol];
        }
        #pragma unroll
        for (int c4 = 0; c4 < 8; ++c4) {
            float4 av[2], bv[2][3];
            #pragma unroll
            for (int m = 0; m < 2; ++m)
                av[m] = *(float4*)&As[buf][bg * 2 + m][c4 * 4];
            #pragma unroll
            for (int js = 0; js < 2; ++js)
                #pragma unroll
                for (int g = 0; g < 3; ++g)
                    bv[js][g] = *(float4*)&Bs[buf][g * 32 + jj + 16 * js][c4 * 4];
            #pragma unroll
            for (int m = 0; m < 2; ++m)
                #pragma unroll
                for (int js = 0; js < 2; ++js)
                    #pragma unroll
                    for (int g = 0; g < 3; ++g)
                        acc[m][js][g] += dot4(av[m], bv[js][g]);
        }
        buf ^= 1;
    }

    #pragma unroll
    for (int m = 0; m < 2; ++m) {
        const int b = btile + bg * 2 + m;
        #pragma unroll
        for (int js = 0; js < 2; ++js) {
            const int j = jtile + jj + 16 * js;
            float hr = acc[m][js][0] + bhh[j];
            float hz = acc[m][js][1] + bhh[DM + j];
            float hn = acc[m][js][2] + bhh[2 * DM + j];
            float r = sigmoidf_(pg[m][js][0] + hr);
            float z = sigmoidf_(pg[m][js][1] + hz);
            float n = tanhf(pg[m][js][2] + r * hn);
            float hv = (1.f - z) * n + z * php[m][js];
            hout[b * DM + j] = hv;
            E[(size_t)(b * LT + t) * 1024 + yoff + j] = hv;
        }
    }
}

// ---------------------------------------------------------------------------
// Chunked k/v projection (rows [r0, r0+16384)) -> temp T, then copy4 back.
// ---------------------------------------------------------------------------
__global__ __launch_bounds__(256) void kv_chunk_kernel(
    const float* __restrict__ E,
    const float* __restrict__ wk, const float* __restrict__ wv,
    const float* __restrict__ kb, const float* __restrict__ vb,
    float* __restrict__ T, int r0)
{
    __shared__ float As[64][36];
    __shared__ float Bk[64][36];
    __shared__ float Bv[64][36];
    const int tid = threadIdx.x;
    const int nn = tid & 15, bb = tid >> 4;
    const int ntile = blockIdx.x * 64;
    const int mtile = blockIdx.y * 64;

    float ak[4][4], av_[4][4];
    #pragma unroll
    for (int m = 0; m < 4; ++m)
        #pragma unroll
        for (int i = 0; i < 4; ++i) { ak[m][i] = 0.f; av_[m][i] = 0.f; }

    const int lrow = tid >> 3;
    const int lcol = (tid & 7) * 4;

    for (int k0 = 0; k0 < 1024; k0 += 32) {
        __syncthreads();
        *(float4*)&As[lrow][lcol] =
            *(const float4*)&E[(size_t)(r0 + mtile + lrow) * 1024 + k0 + lcol];
        *(float4*)&As[lrow + 32][lcol] =
            *(const float4*)&E[(size_t)(r0 + mtile + lrow + 32) * 1024 + k0 + lcol];
        *(float4*)&Bk[lrow][lcol] =
            *(const float4*)&wk[(ntile + lrow) * 1024 + k0 + lcol];
        *(float4*)&Bk[lrow + 32][lcol] =
            *(const float4*)&wk[(ntile + lrow + 32) * 1024 + k0 + lcol];
        *(float4*)&Bv[lrow][lcol] =
            *(const float4*)&wv[(ntile + lrow) * 1024 + k0 + lcol];
        *(float4*)&Bv[lrow + 32][lcol] =
            *(const float4*)&wv[(ntile + lrow + 32) * 1024 + k0 + lcol];
        __syncthreads();
        #pragma unroll
        for (int c4 = 0; c4 < 8; ++c4) {
            float4 a4[4], k4[4], v4[4];
            #pragma unroll
            for (int m = 0; m < 4; ++m) a4[m] = *(float4*)&As[bb + 16 * m][c4 * 4];
            #pragma unroll
            for (int i = 0; i < 4; ++i) {
                k4[i] = *(float4*)&Bk[nn + 16 * i][c4 * 4];
                v4[i] = *(float4*)&Bv[nn + 16 * i][c4 * 4];
            }
            #pragma unroll
            for (int m = 0; m < 4; ++m)
                #pragma unroll
                for (int i = 0; i < 4; ++i) {
                    ak[m][i]  += dot4(a4[m], k4[i]);
                    av_[m][i] += dot4(a4[m], v4[i]);
                }
        }
    }
    #pragma unroll
    for (int m = 0; m < 4; ++m) {
        const int lm = mtile + bb + 16 * m;
        #pragma unroll
        for (int i = 0; i < 4; ++i) {
            const int gn = ntile + nn + 16 * i;
            T[(size_t)lm * 1024 + gn]       = ak[m][i]  + kb[gn];
            T[(size_t)lm * 1024 + DM + gn]  = av_[m][i] + vb[gn];
        }
    }
}

__global__ __launch_bounds__(256) void copy4_kernel(
    float4* __restrict__ dst, const float4* __restrict__ src, int n4)
{
    int i = blockIdx.x * 256 + threadIdx.x;
    const int stride = gridDim.x * 256;
    for (; i < n4; i += stride) dst[i] = src[i];
}

// ---------------------------------------------------------------------------
// h0 = tanh([hF|hB] @ hpost_W.T + hpost_b). One block per batch row.
// ---------------------------------------------------------------------------
__global__ __launch_bounds__(256) void hpost_kernel(
    const float* __restrict__ hF, const float* __restrict__ hB,
    const float* __restrict__ W, const float* __restrict__ bias,
    float* __restrict__ out)
{
    const int b = blockIdx.x;
    __shared__ float as_[1024];
    for (int i = threadIdx.x; i < DM; i += 256) {
        as_[i]      = hF[b * DM + i];
        as_[DM + i] = hB[b * DM + i];
    }
    __syncthreads();
    for (int n = threadIdx.x; n < DM; n += 256) {
        const float* wr = &W[n * 1024];
        float acc = 0.f;
        for (int j = 0; j < 1024; j += 4)
            acc += dot4(*(const float4*)&as_[j], *(const float4*)&wr[j]);
        out[b * DM + n] = tanhf(acc + bias[n]);
    }
}

// ---------------------------------------------------------------------------
// Decoder GRU GEMM, phase-split: bz=0 -> a_o @ dec_Wih[:,512:],
// bz=1 -> h_in @ dec_Whh. 32x32 tile, 2x2 micro-tile, partials -> P.
// grid (16,8,2) = 256 blocks, 256 thr.
// ---------------------------------------------------------------------------
__global__ __launch_bounds__(256) void dec_step_kernel(
    const float* __restrict__ dec_Wih, const float* __restrict__ dec_Whh,
    const float* __restrict__ a_o, const float* __restrict__ h_in,
    float* __restrict__ P)
{
    const int ph = blockIdx.z;
    const float* Aptr = ph ? h_in : a_o;
    const float* Wsrc = ph ? dec_Whh : dec_Wih;
    const size_t wstride = ph ? 512 : 1024;
    const int woff = ph ? 0 : DM;

    __shared__ float As[2][32][36];
    __shared__ float Bs[2][96][36];

    const int tid = threadIdx.x;
    const int jj  = tid & 15;
    const int bg  = tid >> 4;
    const int jtile = blockIdx.x * 32;
    const int btile = blockIdx.y * 32;

    float acc[2][2][3];
    #pragma unroll
    for (int m = 0; m < 2; ++m)
        #pragma unroll
        for (int js = 0; js < 2; ++js)
            #pragma unroll
            for (int g = 0; g < 3; ++g) acc[m][js][g] = 0.f;

    const int lrow = tid >> 3;
    const int lcol = (tid & 7) * 4;
    size_t wbase[3];
    #pragma unroll
    for (int rr = 0; rr < 3; ++rr)
        wbase[rr] = (size_t)(rr * DM + jtile + lrow) * wstride + woff;

    float4 rA  = *(const float4*)&Aptr[(btile + lrow) * DM + lcol];
    float4 rB0 = *(const float4*)&Wsrc[wbase[0] + lcol];
    float4 rB1 = *(const float4*)&Wsrc[wbase[1] + lcol];
    float4 rB2 = *(const float4*)&Wsrc[wbase[2] + lcol];

    int buf = 0;
    for (int kc = 0; kc < 16; ++kc) {
        *(float4*)&As[buf][lrow][lcol]      = rA;
        *(float4*)&Bs[buf][lrow][lcol]      = rB0;
        *(float4*)&Bs[buf][lrow + 32][lcol] = rB1;
        *(float4*)&Bs[buf][lrow + 64][lcol] = rB2;
        __syncthreads();
        if (kc < 15) {
            const int k0 = (kc + 1) * 32;
            rA  = *(const float4*)&Aptr[(btile + lrow) * DM + k0 + lcol];
            rB0 = *(const float4*)&Wsrc[wbase[0] + k0 + lcol];
            rB1 = *(const float4*)&Wsrc[wbase[1] + k0 + lcol];
            rB2 = *(const float4*)&Wsrc[wbase[2] + k0 + lcol];
        }
        #pragma unroll
        for (int c4 = 0; c4 < 8; ++c4) {
            float4 av[2], bv[2][3];
            #pragma unroll
            for (int m = 0; m < 2; ++m)
                av[m] = *(float4*)&As[buf][bg * 2 + m][c4 * 4];
            #pragma unroll
            for (int js = 0; js < 2; ++js)
                #pragma unroll
                for (int g = 0; g < 3; ++g)
                    bv[js][g] = *(float4*)&Bs[buf][g * 32 + jj + 16 * js][c4 * 4];
            #pragma unroll
            for (int m = 0; m < 2; ++m)
                #pragma unroll
                for (int js = 0; js < 2; ++js)
                    #pragma unroll
                    for (int g = 0; g < 3; ++g)
                        acc[m][js][g] += dot4(av[m], bv[js][g]);
        }
        buf ^= 1;
    }

    float* Pp = P + (size_t)ph * B * 1536;
    #pragma unroll
    for (int m = 0; m < 2; ++m) {
        const int b = btile + bg * 2 + m;
        #pragma unroll
        for (int js = 0; js < 2; ++js) {
            const int j = jtile + jj + 16 * js;
            #pragma unroll
            for (int g = 0; g < 3; ++g)
                Pp[(size_t)b * 1536 + g * 512 + j] = acc[m][js][g];
        }
    }
}

// ---------------------------------------------------------------------------
// Decoder tail, 512 threads, one block per batch row:
// combine(P0+P1 -> gates -> x, h_out) | logits+argmax | quad-QK attention
// + quad-PV. K row r at EKV[r*1024], V at +512.
// ---------------------------------------------------------------------------
__global__ __launch_bounds__(512) void dec_attend_post_kernel(
    const float* __restrict__ P,
    const float* __restrict__ Gd, const float* __restrict__ dec_bhh,
    const float* __restrict__ h_in, float* __restrict__ h_out,
    const float* __restrict__ q_init,
    const float* __restrict__ EKV,
    const float* __restrict__ post_W, const float* __restrict__ post_b,
    float* __restrict__ attn, float* __restrict__ res,
    float* __restrict__ a_o, int* __restrict__ dec_i,
    int s, int attn_row, int do_combine, int do_post, int do_attn)
{
    const int b = blockIdx.x;
    const int tid = threadIdx.x;
    __shared__ float qs[DM];
    __shared__ float part[512];
    __shared__ float sarr[LT];
    __shared__ float red[2];
    __shared__ float4 pvp[4][128];

    if (do_combine) {
        const int j = tid;                       // 0..511
        const int c = dec_i[b];
        const float* P0 = P + (size_t)b * 1536;
        const float* P1 = P + (size_t)B * 1536 + (size_t)b * 1536;
        float rsum = P0[j] + P1[j];
        float zsum = P0[512 + j] + P1[512 + j];
        float r = sigmoidf_(Gd[c * D3 + j] + dec_bhh[j] + rsum);
        float z = sigmoidf_(Gd[c * D3 + DM + j] + dec_bhh[DM + j] + zsum);
        float n = tanhf(Gd[c * D3 + 2 * DM + j] + P0[1024 + j]
                        + r * (P1[1024 + j] + dec_bhh[2 * DM + j]));
        float x = (1.f - z) * n + z * h_in[b * DM + j];
        qs[j] = x;
        h_out[b * DM + j] = x;
    } else if (tid < 128) {
        *(float4*)&qs[tid * 4] = *(const float4*)&q_init[b * DM + tid * 4];
    }
    __syncthreads();

    if (do_post) {
        if (tid < DPH) {
            const float* wr = &post_W[tid * DM];
            float acc = 0.f;
            for (int d = 0; d < DM; d += 4)
                acc += dot4(*(const float4*)&qs[d], *(const float4*)&wr[d]);
            float lv = acc + post_b[tid];
            res[(size_t)(b * LP + s) * DPH + tid] = lv;
            part[tid] = lv;
        }
        __syncthreads();
        if (tid == 0) {   // first-occurrence argmax, matching jnp.argmax
            float best = part[0]; int bi = 0;
            for (int p = 1; p < DPH; ++p) {
                float vv = part[p];
                if (vv > best) { best = vv; bi = p; }
            }
            dec_i[b] = bi;
        }
        __syncthreads();
    }

    if (do_attn) {
        // --- scores: 4 threads per K-row (d-quarters) ---
        {
            const int r = tid & 127, quad = tid >> 7;
            const float* kr = &EKV[(size_t)(b * LT + r) * 1024 + quad * 128];
            const float* qh = &qs[quad * 128];
            float p0 = 0.f, p1 = 0.f;
            #pragma unroll
            for (int d = 0; d < 128; d += 8) {
                p0 += dot4(*(const float4*)&qh[d],     *(const float4*)&kr[d]);
                p1 += dot4(*(const float4*)&qh[d + 4], *(const float4*)&kr[d + 4]);
            }
            part[tid] = p0 + p1;
        }
        __syncthreads();
        if (tid < LT)
            sarr[tid] = (((part[tid] + part[tid + 128]) + part[tid + 256])
                         + part[tid + 384]) * SCALE_F;
        __syncthreads();
        if (tid < 64) {
            float m = fmaxf(sarr[tid], sarr[tid + 64]);
            #pragma unroll
            for (int off = 32; off > 0; off >>= 1)
                m = fmaxf(m, __shfl_xor(m, off));
            if (tid == 0) red[0] = m;
        }
        __syncthreads();
        const float smax = red[0];
        if (tid < LT) sarr[tid] = expf(sarr[tid] - smax);
        __syncthreads();
        if (tid < 64) {
            float ssum = sarr[tid] + sarr[tid + 64];
            #pragma unroll
            for (int off = 32; off > 0; off >>= 1)
                ssum += __shfl_xor(ssum, off);
            if (tid == 0) red[1] = ssum;
        }
        __syncthreads();
        const float inv = 1.0f / red[1];
        if (tid < LT) {
            float a = sarr[tid] * inv;
            sarr[tid] = a;
            attn[(size_t)(b * LP + attn_row) * LT + tid] = a;
        }
        __syncthreads();
        // --- o = a @ V: 4 threads per d-float4 (l-quarters) ---
        {
            const int d4 = tid & 127, quad = tid >> 7;
            const float* vb0 = &EKV[(size_t)b * LT * 1024 + DM];
            float4 a0 = make_float4(0.f, 0.f, 0.f, 0.f);
            float4 a1 = make_float4(0.f, 0.f, 0.f, 0.f);
            const int l0 = quad * 32;
            #pragma unroll
            for (int l = l0; l < l0 + 32; l += 2) {
                float w0 = sarr[l], w1 = sarr[l + 1];
                float4 v0 = *(const float4*)&vb0[(size_t)l * 1024 + d4 * 4];
                float4 v1 = *(const float4*)&vb0[(size_t)(l + 1) * 1024 + d4 * 4];
                a0.x += w0 * v0.x; a0.y += w0 * v0.y;
                a0.z += w0 * v0.z; a0.w += w0 * v0.w;
                a1.x += w1 * v1.x; a1.y += w1 * v1.y;
                a1.z += w1 * v1.z; a1.w += w1 * v1.w;
            }
            pvp[quad][d4] = make_float4(a0.x + a1.x, a0.y + a1.y,
                                        a0.z + a1.z, a0.w + a1.w);
        }
        __syncthreads();
        if (tid < 128) {
            float4 p0 = pvp[0][tid], p1 = pvp[1][tid];
            float4 p2 = pvp[2][tid], p3 = pvp[3][tid];
            float4 o = make_float4(((p0.x + p1.x) + p2.x) + p3.x,
                                   ((p0.y + p1.y) + p2.y) + p3.y,
                                   ((p0.z + p1.z) + p2.z) + p3.z,
                                   ((p0.w + p1.w) + p2.w) + p3.w);
            *(float4*)&a_o[b * DM + tid * 4] = o;
        }
    }
}

// ---------------------------------------------------------------------------
extern "C" void kernel_launch(void* const* d_in, const int* in_sizes, int n_in,
                              void* d_out, int out_size, void* d_ws, size_t ws_size,
                              hipStream_t stream)
{
    const int*   text    = (const int*)d_in[0];
    const float* E_alpha = (const float*)d_in[2];
    const float* Wih_f   = (const float*)d_in[3];
    const float* Whh_f   = (const float*)d_in[4];
    const float* bih_f   = (const float*)d_in[5];
    const float* bhh_f   = (const float*)d_in[6];
    const float* Wih_b   = (const float*)d_in[7];
    const float* Whh_b   = (const float*)d_in[8];
    const float* bih_b   = (const float*)d_in[9];
    const float* bhh_b   = (const float*)d_in[10];
    const float* hpost_W = (const float*)d_in[11];
    const float* hpost_b = (const float*)d_in[12];
    const float* wk_W    = (const float*)d_in[13];
    const float* wk_b    = (const float*)d_in[14];
    const float* wv_W    = (const float*)d_in[15];
    const float* wv_b    = (const float*)d_in[16];
    const float* E_ph    = (const float*)d_in[17];
    const float* dec_Wih = (const float*)d_in[18];
    const float* dec_Whh = (const float*)d_in[19];
    const float* dec_bih = (const float*)d_in[20];
    const float* dec_bhh = (const float*)d_in[21];
    const float* post_W  = (const float*)d_in[22];
    const float* post_b  = (const float*)d_in[23];

    float* ws = (float*)d_ws;
    float* Gf  = ws;                 // 100*1536
    float* Gb  = Gf  + 153600;
    float* Gd  = Gb  + 153600;       // 80*1536
    float* hF0 = Gd  + 122880;
    float* hF1 = hF0 + 131072;
    float* hB0 = hF1 + 131072;
    float* hB1 = hB0 + 131072;
    float* hd0 = hB1 + 131072;
    float* hd1 = hd0 + 131072;
    float* a_o = hd1 + 131072;
    int*   dec_i = (int*)(a_o + 131072);
    float* P   = a_o + 131072 + 512; // 2*256*1536 gate partials (3 MB)
    float* E   = P + 786432;         // 32768*1024: ys, then in-place K|V
    float* T   = E + 33554432;       // 16384*1024 chunk temp (64 MB)
    // ~200 MB total

    hipMemsetAsync(hF0, 0, 131072 * sizeof(float), stream);
    hipMemsetAsync(hB0, 0, 131072 * sizeof(float), stream);
    hipMemsetAsync(dec_i, 0, B * sizeof(int), stream);

    precompG_kernel<<<dim3(6, 25), 256, 0, stream>>>(E_alpha, Wih_f, bih_f, Gf, DM, 0);
    precompG_kernel<<<dim3(6, 25), 256, 0, stream>>>(E_alpha, Wih_b, bih_b, Gb, DM, 0);
    precompG_kernel<<<dim3(6, 20), 256, 0, stream>>>(E_ph, dec_Wih, dec_bih, Gd, 1024, 0);

    // Bidirectional encoder: 128 steps
    for (int s = 0; s < LT; ++s) {
        const float* fin = (s & 1) ? hF1 : hF0;
        float*       fou = (s & 1) ? hF0 : hF1;
        const float* bin = (s & 1) ? hB1 : hB0;
        float*       bou = (s & 1) ? hB0 : hB1;
        enc_step_kernel<<<dim3(16, 8, 2), 256, 0, stream>>>(
            Gf, Gb, Whh_f, Whh_b, bhh_f, bhh_b, text,
            fin, fou, bin, bou, E, s);
    }
    // s=127 wrote into hF0/hB0 -> finals live there

    for (int c = 0; c < 2; ++c) {
        const int r0 = c * 16384;
        kv_chunk_kernel<<<dim3(8, 256), 256, 0, stream>>>(
            E, wk_W, wv_W, wk_b, wv_b, T, r0);
        copy4_kernel<<<dim3(4096), 256, 0, stream>>>(
            (float4*)(E + (size_t)r0 * 1024), (const float4*)T,
            16384 * 1024 / 4);
    }

    hpost_kernel<<<dim3(B), 256, 0, stream>>>(hF0, hB0, hpost_W, hpost_b, hd0);

    float* attn = (float*)d_out;                  // (256,64,128)
    float* res  = attn + (size_t)B * LP * LT;     // (256,64,80)

    // initial attend: q = hd0 -> attn row 0 + a_o
    dec_attend_post_kernel<<<dim3(B), 512, 0, stream>>>(
        P, Gd, dec_bhh, hd0, hd1, hd0, E, post_W, post_b,
        attn, res, a_o, dec_i,
        /*s=*/0, /*attn_row=*/0, /*combine=*/0, /*post=*/0, /*attn=*/1);

    for (int s = 0; s < LP; ++s) {
        const float* hin = (s & 1) ? hd1 : hd0;
        float*       hou = (s & 1) ? hd0 : hd1;
        // phase-split GRU GEMM -> partials P
        dec_step_kernel<<<dim3(16, 8, 2), 256, 0, stream>>>(
            dec_Wih, dec_Whh, a_o, hin, P);
        // combine + gates + x write + logits/argmax + attention
        dec_attend_post_kernel<<<dim3(B), 512, 0, stream>>>(
            P, Gd, dec_bhh, hin, hou, hd0 /*unused*/, E, post_W, post_b,
            attn, res, a_o, dec_i,
            s, s + 1, /*combine=*/1, /*post=*/1, /*attn=*/(s < LP - 1) ? 1 : 0);
    }
}